// Round 5
// baseline (273.357 us; speedup 1.0000x reference)
//
#include <hip/hip_runtime.h>

// out = (I + W + ... + W^10) x == M . x  (M 256x256, exactly banded +-70).
// K1: build M per column, split-precision bf16 Mh/Ml (row-major).
// K2: banded MFMA GEMM. Per 32-wide spatial tile: register-prefetched float4
//     loads -> one cooperative bf16 hi/lo split -> double-buffered LDS in
//     B-frag word layout ([k/2][n] packed pairs, ONE barrier per tile) ->
//     per-wave banded MFMA with zero-chunk skip. Grid 512 = 2 blocks/CU.

#define NCH 256
#define PAD 7
#define SCOPE 15
#define SPATIAL 3136
#define PER_B 802816          // 256*3136
#define STW 32                // spatial tile width
#define STILES_PER_B 98       // 3136/32
#define NTILES 3136           // 32*98
#define GRID_APPLY 512
#define MAXCH 12              // max K-chunks (of 16) per wave band window

typedef __attribute__((ext_vector_type(8))) __bf16 bf16x8;
typedef __attribute__((ext_vector_type(16))) float float16;
typedef __attribute__((ext_vector_type(4))) unsigned int uint4v;

static __device__ __forceinline__ unsigned short f2bf_rn_u(float f) {
  unsigned u = __builtin_bit_cast(unsigned int, f);
  return (unsigned short)((u + 0x7FFFu + ((u >> 16) & 1u)) >> 16);
}
static __device__ __forceinline__ float bf2f_u(unsigned short h) {
  unsigned u = ((unsigned)h) << 16;
  return __builtin_bit_cast(float, u);
}
static __device__ __forceinline__ unsigned pack_bf2(float a, float b) {
  return (unsigned)f2bf_rn_u(a) | ((unsigned)f2bf_rn_u(b) << 16);
}
// split floats (a,b) -> hi packed word + lo (residual) packed word
static __device__ __forceinline__ void split2(float a, float b,
                                              unsigned& h, unsigned& l) {
  h = pack_bf2(a, b);
  const float ra = a - __builtin_bit_cast(float, h << 16);
  const float rb = b - __builtin_bit_cast(float, h & 0xFFFF0000u);
  l = pack_bf2(ra, rb);
}

// ---- Kernel 1: build M column d (block d), write bf16 hi/lo row-major ----
__global__ void build_M_kernel(const float* __restrict__ w,
                               const int* __restrict__ max_steps_p,
                               unsigned short* __restrict__ Mh,
                               unsigned short* __restrict__ Ml) {
  const int d = blockIdx.x;
  const int c = threadIdx.x;
  __shared__ float v[2][NCH];
  __shared__ float wsh[SCOPE];
  if (c < SCOPE) wsh[c] = w[c];
  const float e = (c == d) ? 1.0f : 0.0f;
  v[0][c] = e;
  __syncthreads();
  const int steps = *max_steps_p;
  int cur = 0;
  for (int t = 0; t < steps; ++t) {
    float s = e;
#pragma unroll
    for (int j = 0; j < SCOPE; ++j) {
      const int cc = c + j - PAD;
      if (cc >= 0 && cc < NCH) s += wsh[j] * v[cur][cc];
    }
    cur ^= 1;
    v[cur][c] = s;
    __syncthreads();
  }
  const float f = v[cur][c];
  const unsigned short h = f2bf_rn_u(f);
  Mh[c * NCH + d] = h;
  Ml[c * NCH + d] = f2bf_rn_u(f - bf2f_u(h));
}

// ---- Kernel 2 -------------------------------------------------------------
// 512 threads (8 waves); wave w -> output channels [32w,32w+32).
// LDS (double-buffered): HB/LB = packed bf16-pair words, word (k2, n) =
// (bf16(x[2k2][n]), bf16(x[2k2+1][n])); B-frag = 4 ds_read_b32 stride 32
// words (bank-free). One __syncthreads per tile: buffer parity alternates,
// reads of buf p at iter t are ordered before writes of buf p at iter t+2
// by each wave's own barrier at iter t+1.
__global__ __launch_bounds__(512, 4) void apply_M_kernel(
    const float* __restrict__ x, const unsigned short* __restrict__ Mh,
    const unsigned short* __restrict__ Ml, float* __restrict__ out) {
  __shared__ unsigned HB[2][128 * STW];  // 2 x 16 KB
  __shared__ unsigned LB[2][128 * STW];  // 2 x 16 KB

  const int tid  = threadIdx.x;
  const int lane = tid & 63;
  const int w    = tid >> 6;
  const int m    = lane & 31;  // A row in c-tile == B spatial col
  const int half = lane >> 5;  // k-half
  const int c0   = w * 32;

  // exact nonzero band: rows [c0, c0+31] touch cols [c0-70, c0+101]
  int clo = c0 - 70; if (clo < 0) clo = 0; clo >>= 4;
  int chi = c0 + 101; if (chi > 255) chi = 255; chi >>= 4;
  const int nch = chi - clo + 1;  // 7..12 per wave

  bf16x8 Ah[MAXCH], Al[MAXCH];
#pragma unroll
  for (int i = 0; i < MAXCH; ++i) {
    if (i < nch) {
      const int off = (c0 + m) * NCH + (clo + i) * 16 + half * 8;
      Ah[i] = *(const bf16x8*)(Mh + off);
      Al[i] = *(const bf16x8*)(Ml + off);
    }
  }

  // loader geometry: thread -> (d-pair rows dg, dg+64; 4 spatial cols sq..sq+3)
  const int sq = (tid & 7) * 4;
  const int dg = tid >> 3;  // 0..63

  int tau = blockIdx.x;
  float4 g0, g1, g2, g3;
  {
    const float* gb = x + (size_t)(tau / STILES_PER_B) * PER_B
                        + (size_t)(tau % STILES_PER_B) * STW;
    g0 = *(const float4*)(gb + (size_t)(2 * dg) * SPATIAL + sq);
    g1 = *(const float4*)(gb + (size_t)(2 * dg + 1) * SPATIAL + sq);
    g2 = *(const float4*)(gb + (size_t)(2 * dg + 128) * SPATIAL + sq);
    g3 = *(const float4*)(gb + (size_t)(2 * dg + 129) * SPATIAL + sq);
  }

  int buf = 0;
#pragma unroll 1
  for (; tau < NTILES; tau += GRID_APPLY) {
    // cooperative split: registers -> bf16 hi/lo words in B-frag layout
    {
      unsigned h0, h1, h2, h3, l0, l1, l2, l3;
      split2(g0.x, g1.x, h0, l0); split2(g0.y, g1.y, h1, l1);
      split2(g0.z, g1.z, h2, l2); split2(g0.w, g1.w, h3, l3);
      *(uint4v*)&HB[buf][dg * STW + sq] = (uint4v){h0, h1, h2, h3};
      *(uint4v*)&LB[buf][dg * STW + sq] = (uint4v){l0, l1, l2, l3};
      split2(g2.x, g3.x, h0, l0); split2(g2.y, g3.y, h1, l1);
      split2(g2.z, g3.z, h2, l2); split2(g2.w, g3.w, h3, l3);
      *(uint4v*)&HB[buf][(dg + 64) * STW + sq] = (uint4v){h0, h1, h2, h3};
      *(uint4v*)&LB[buf][(dg + 64) * STW + sq] = (uint4v){l0, l1, l2, l3};
    }

    // prefetch next tile into registers (stays in flight across compute)
    const int ntau = tau + GRID_APPLY;
    if (ntau < NTILES) {
      const float* gb = x + (size_t)(ntau / STILES_PER_B) * PER_B
                          + (size_t)(ntau % STILES_PER_B) * STW;
      g0 = *(const float4*)(gb + (size_t)(2 * dg) * SPATIAL + sq);
      g1 = *(const float4*)(gb + (size_t)(2 * dg + 1) * SPATIAL + sq);
      g2 = *(const float4*)(gb + (size_t)(2 * dg + 128) * SPATIAL + sq);
      g3 = *(const float4*)(gb + (size_t)(2 * dg + 129) * SPATIAL + sq);
    }

    __syncthreads();  // HB/LB[buf] complete (sole barrier per tile)

    // three independent accumulator chains (hi*hi, hi*lo, lo*hi)
    float16 a0, a1, a2;
#pragma unroll
    for (int q = 0; q < 16; ++q) { a0[q] = 0.0f; a1[q] = 0.0f; a2[q] = 0.0f; }

#pragma unroll
    for (int i = 0; i < MAXCH; ++i) {
      if (i < nch) {
        const int k2b = (clo + i) * 8 + half * 4;
        const unsigned* hp = &HB[buf][k2b * STW + m];
        const unsigned* lp = &LB[buf][k2b * STW + m];
        const uint4v hw = {hp[0], hp[32], hp[64], hp[96]};
        const uint4v lw = {lp[0], lp[32], lp[64], lp[96]};
        const bf16x8 bh = __builtin_bit_cast(bf16x8, hw);
        const bf16x8 bl = __builtin_bit_cast(bf16x8, lw);
        a0 = __builtin_amdgcn_mfma_f32_32x32x16_bf16(Ah[i], bh, a0, 0, 0, 0);
        a1 = __builtin_amdgcn_mfma_f32_32x32x16_bf16(Ah[i], bl, a1, 0, 0, 0);
        a2 = __builtin_amdgcn_mfma_f32_32x32x16_bf16(Al[i], bh, a2, 0, 0, 0);
      }
    }

    // epilogue: C/D map (32x32): col = lane&31, row = (r&3)+8*(r>>2)+4*half
    const int b  = tau / STILES_PER_B;
    const int s0 = (tau % STILES_PER_B) * STW;
    float* ob = out + (size_t)b * PER_B + (size_t)s0 + m;
#pragma unroll
    for (int r = 0; r < 16; ++r) {
      const int row = (r & 3) + 8 * (r >> 2) + 4 * half;
      ob[(size_t)(c0 + row) * SPATIAL] = a0[r] + a1[r] + a2[r];
    }

    buf ^= 1;
  }
}

extern "C" void kernel_launch(void* const* d_in, const int* in_sizes, int n_in,
                              void* d_out, int out_size, void* d_ws, size_t ws_size,
                              hipStream_t stream) {
  const float* x = (const float*)d_in[0];  // (32, 256, 56, 56) fp32
  const float* w = (const float*)d_in[1];  // (15,) fp32
  const int* ms = (const int*)d_in[2];     // scalar int (10)
  float* out = (float*)d_out;              // (32, 256, 56, 56) fp32

  unsigned short* Mh = (unsigned short*)d_ws;  // 128 KB
  unsigned short* Ml = Mh + NCH * NCH;         // 128 KB

  build_M_kernel<<<NCH, NCH, 0, stream>>>(w, ms, Mh, Ml);
  apply_M_kernel<<<GRID_APPLY, 512, 0, stream>>>(x, Mh, Ml, out);
}